// Round 1
// baseline (725.821 us; speedup 1.0000x reference)
//
#include <hip/hip_runtime.h>

#define N_NODES 100000
#define N_EDGES 1600000
#define DIM 128
#define NC 40

// ---------------- CSR build ----------------
__global__ __launch_bounds__(256) void k_hist(const int2* __restrict__ ei, int* __restrict__ deg) {
    int i = blockIdx.x * 256 + threadIdx.x;
    if (i < N_EDGES) {
        int2 e = ei[i];
        atomicAdd(&deg[e.y + 1], 1);
    }
}

#define SCAN_N (N_NODES + 1)
#define SCAN_T 256
#define SCAN_PER 32
#define SCAN_CHUNK (SCAN_T * SCAN_PER)                      // 8192
#define SCAN_NB ((SCAN_N + SCAN_CHUNK - 1) / SCAN_CHUNK)    // 13

__global__ __launch_bounds__(SCAN_T) void k_scan1(int* __restrict__ a, int* __restrict__ bsums) {
    __shared__ int wtot[SCAN_T / 64];
    int t = threadIdx.x, lane = t & 63, wid = t >> 6;
    int base = blockIdx.x * SCAN_CHUNK + t * SCAN_PER;
    int v[SCAN_PER];
    int run = 0;
    #pragma unroll
    for (int j = 0; j < SCAN_PER; ++j) {
        int idx = base + j;
        int x = (idx < SCAN_N) ? a[idx] : 0;
        run += x;
        v[j] = run;
    }
    int incl = run;
    #pragma unroll
    for (int d = 1; d < 64; d <<= 1) {
        int u = __shfl_up(incl, d, 64);
        if (lane >= d) incl += u;
    }
    if (lane == 63) wtot[wid] = incl;
    __syncthreads();
    int add = incl - run;
    for (int w = 0; w < wid; ++w) add += wtot[w];
    #pragma unroll
    for (int j = 0; j < SCAN_PER; ++j) {
        int idx = base + j;
        if (idx < SCAN_N) a[idx] = v[j] + add;
    }
    if (t == 0) {
        int tot = 0;
        for (int w = 0; w < SCAN_T / 64; ++w) tot += wtot[w];
        bsums[blockIdx.x] = tot;
    }
}

__global__ __launch_bounds__(SCAN_T) void k_scan2(int* __restrict__ a, const int* __restrict__ bsums) {
    int off = 0;
    for (int i = 0; i < (int)blockIdx.x; ++i) off += bsums[i];
    int base = blockIdx.x * SCAN_CHUNK + threadIdx.x;
    #pragma unroll
    for (int j = 0; j < SCAN_PER; ++j) {
        int idx = base + j * SCAN_T;
        if (idx < SCAN_N) a[idx] += off;
    }
}

__global__ __launch_bounds__(256) void k_fill(const int2* __restrict__ ei, const int* __restrict__ row_ptr,
                                              int* __restrict__ cursor, int* __restrict__ csr_src) {
    int i = blockIdx.x * 256 + threadIdx.x;
    if (i < N_EDGES) {
        int2 e = ei[i];
        int p = atomicAdd(&cursor[e.y], 1);
        csr_src[row_ptr[e.y] + p] = e.x;
    }
}

// ---------------- layer 1 aggregation: hpre = x + segsum(x[src]) ----------------
__global__ __launch_bounds__(256) void k_gather1(const float* __restrict__ x, const int* __restrict__ row_ptr,
                                                 const int* __restrict__ csr_src, float* __restrict__ hpre) {
    int lane = threadIdx.x & 63, wid = threadIdx.x >> 6;
    int n = blockIdx.x * 4 + wid;
    float2 acc = ((const float2*)(x + (size_t)n * DIM))[lane];
    int i = row_ptr[n], e = row_ptr[n + 1];
    for (; i + 4 <= e; i += 4) {
        int s0 = csr_src[i], s1 = csr_src[i + 1], s2 = csr_src[i + 2], s3 = csr_src[i + 3];
        float2 v0 = ((const float2*)(x + (size_t)s0 * DIM))[lane];
        float2 v1 = ((const float2*)(x + (size_t)s1 * DIM))[lane];
        float2 v2 = ((const float2*)(x + (size_t)s2 * DIM))[lane];
        float2 v3 = ((const float2*)(x + (size_t)s3 * DIM))[lane];
        acc.x += (v0.x + v1.x) + (v2.x + v3.x);
        acc.y += (v0.y + v1.y) + (v2.y + v3.y);
    }
    for (; i < e; ++i) {
        int s = csr_src[i];
        float2 v = ((const float2*)(x + (size_t)s * DIM))[lane];
        acc.x += v.x; acc.y += v.y;
    }
    ((float2*)(hpre + (size_t)n * DIM))[lane] = acc;
}

// ---------------- layer 1 MLP (fused, in-place): x2 = relu(relu(h@W1a+b1a)@W1b+b1b) ----------------
__global__ __launch_bounds__(256) void k_mlp1(float* __restrict__ hx,
                                              const float* __restrict__ W1a, const float* __restrict__ b1a,
                                              const float* __restrict__ W1b, const float* __restrict__ b1b) {
    __shared__ float in_t[32][DIM];
    __shared__ float h_t[32][DIM];
    int t = threadIdx.x;
    size_t row0 = (size_t)blockIdx.x * 32;
    for (int i = t; i < 32 * (DIM / 4); i += 256) {
        int r = i >> 5, c4 = i & 31;
        ((float4*)in_t[r])[c4] = ((const float4*)(hx + (row0 + r) * DIM))[c4];
    }
    __syncthreads();
    int cg = t & 31, rg = t >> 5;
    int c0 = cg * 4, r0 = rg * 4;
    float acc[4][4];
    float4 ba = *(const float4*)(b1a + c0);
    #pragma unroll
    for (int j = 0; j < 4; ++j) { acc[j][0] = ba.x; acc[j][1] = ba.y; acc[j][2] = ba.z; acc[j][3] = ba.w; }
    #pragma unroll 4
    for (int k = 0; k < DIM; ++k) {
        float4 w = *(const float4*)(W1a + (size_t)k * DIM + c0);
        #pragma unroll
        for (int j = 0; j < 4; ++j) {
            float a = in_t[r0 + j][k];
            acc[j][0] += a * w.x; acc[j][1] += a * w.y; acc[j][2] += a * w.z; acc[j][3] += a * w.w;
        }
    }
    #pragma unroll
    for (int j = 0; j < 4; ++j) {
        float4 h;
        h.x = fmaxf(acc[j][0], 0.f); h.y = fmaxf(acc[j][1], 0.f);
        h.z = fmaxf(acc[j][2], 0.f); h.w = fmaxf(acc[j][3], 0.f);
        *(float4*)&h_t[r0 + j][c0] = h;
    }
    __syncthreads();
    float4 bb = *(const float4*)(b1b + c0);
    #pragma unroll
    for (int j = 0; j < 4; ++j) { acc[j][0] = bb.x; acc[j][1] = bb.y; acc[j][2] = bb.z; acc[j][3] = bb.w; }
    #pragma unroll 4
    for (int k = 0; k < DIM; ++k) {
        float4 w = *(const float4*)(W1b + (size_t)k * DIM + c0);
        #pragma unroll
        for (int j = 0; j < 4; ++j) {
            float a = h_t[r0 + j][k];
            acc[j][0] += a * w.x; acc[j][1] += a * w.y; acc[j][2] += a * w.z; acc[j][3] += a * w.w;
        }
    }
    #pragma unroll
    for (int j = 0; j < 4; ++j) {
        float4 o;
        o.x = fmaxf(acc[j][0], 0.f); o.y = fmaxf(acc[j][1], 0.f);
        o.z = fmaxf(acc[j][2], 0.f); o.w = fmaxf(acc[j][3], 0.f);
        *(float4*)(hx + (row0 + r0 + j) * DIM + c0) = o;
    }
}

// ---------------- y = x2 @ W2a (bias deferred; aggregation pushed past the matmul) ----------------
__global__ __launch_bounds__(256) void k_gemm_y(const float* __restrict__ x2, const float* __restrict__ W2a,
                                                float* __restrict__ y) {
    __shared__ float in_t[32][DIM + 4];
    int t = threadIdx.x;
    size_t row0 = (size_t)blockIdx.x * 32;
    for (int i = t; i < 32 * (DIM / 4); i += 256) {
        int r = i >> 5, c4 = i & 31;
        ((float4*)in_t[r])[c4] = ((const float4*)(x2 + (row0 + r) * DIM))[c4];
    }
    __syncthreads();
    int r = t >> 3, c0 = (t & 7) * 5;
    float acc[5] = {0.f, 0.f, 0.f, 0.f, 0.f};
    #pragma unroll 4
    for (int k = 0; k < DIM; ++k) {
        float a = in_t[r][k];
        #pragma unroll
        for (int j = 0; j < 5; ++j) acc[j] += a * W2a[(size_t)k * NC + c0 + j];
    }
    #pragma unroll
    for (int j = 0; j < 5; ++j) y[(row0 + r) * NC + c0 + j] = acc[j];
}

// ---------------- z = y + segsum(y[src]); h2 = relu(z+b2a); out = softmax(h2@W2b+b2b) ----------------
__global__ __launch_bounds__(256) void k_gather2(const float* __restrict__ y, const int* __restrict__ row_ptr,
                                                 const int* __restrict__ csr_src, const float* __restrict__ b2a,
                                                 const float* __restrict__ W2b, const float* __restrict__ b2b,
                                                 float* __restrict__ out) {
    __shared__ float h2s[4][NC];
    int lane = threadIdx.x & 63, wid = threadIdx.x >> 6;
    int n = blockIdx.x * 4 + wid;
    float acc = 0.f;
    if (lane < NC) acc = y[(size_t)n * NC + lane];
    int i = row_ptr[n], e = row_ptr[n + 1];
    for (; i + 4 <= e; i += 4) {
        int s0 = csr_src[i], s1 = csr_src[i + 1], s2 = csr_src[i + 2], s3 = csr_src[i + 3];
        if (lane < NC) {
            acc += (y[(size_t)s0 * NC + lane] + y[(size_t)s1 * NC + lane]) +
                   (y[(size_t)s2 * NC + lane] + y[(size_t)s3 * NC + lane]);
        }
    }
    for (; i < e; ++i) {
        int s = csr_src[i];
        if (lane < NC) acc += y[(size_t)s * NC + lane];
    }
    if (lane < NC) h2s[wid][lane] = fmaxf(acc + b2a[lane], 0.f);
    __syncthreads();
    float logit = -__builtin_inff();
    if (lane < NC) {
        float a = b2b[lane];
        #pragma unroll 4
        for (int k = 0; k < NC; ++k) a += h2s[wid][k] * W2b[k * NC + lane];
        logit = a;
    }
    float m = logit;
    #pragma unroll
    for (int d = 32; d >= 1; d >>= 1) m = fmaxf(m, __shfl_xor(m, d, 64));
    float ev = (lane < NC) ? __expf(logit - m) : 0.f;
    float s = ev;
    #pragma unroll
    for (int d = 32; d >= 1; d >>= 1) s += __shfl_xor(s, d, 64);
    if (lane < NC) out[(size_t)n * NC + lane] = ev / s;
}

extern "C" void kernel_launch(void* const* d_in, const int* in_sizes, int n_in,
                              void* d_out, int out_size, void* d_ws, size_t ws_size,
                              hipStream_t stream) {
    const float* x   = (const float*)d_in[0];
    const int2*  ei  = (const int2*)d_in[1];
    const float* W1a = (const float*)d_in[2];
    const float* b1a = (const float*)d_in[3];
    const float* W1b = (const float*)d_in[4];
    const float* b1b = (const float*)d_in[5];
    const float* W2a = (const float*)d_in[6];
    const float* b2a = (const float*)d_in[7];
    const float* W2b = (const float*)d_in[8];
    const float* b2b = (const float*)d_in[9];
    float* out = (float*)d_out;

    char* w = (char*)d_ws;
    int*   deg    = (int*)(w + 0);           // 100001 ints, becomes row_ptr after scan
    int*   cursor = (int*)(w + 400004);      // 100000 ints
    int*   bsums  = (int*)(w + 800004);      // 16 ints
    int*   csr    = (int*)(w + 800128);      // 1.6M ints (src ids grouped by dst)
    float* hpre   = (float*)(w + 7200256);   // 100000x128 (hpre -> x2 in-place)
    float* y      = (float*)(w + 58400256);  // 100000x40
    // total ws needed: 74,400,256 bytes

    hipMemsetAsync(w, 0, 800068, stream);  // zero deg + cursor (+bsums)
    k_hist  <<<N_EDGES / 256, 256, 0, stream>>>(ei, deg);
    k_scan1 <<<SCAN_NB, SCAN_T, 0, stream>>>(deg, bsums);
    k_scan2 <<<SCAN_NB, SCAN_T, 0, stream>>>(deg, bsums);
    k_fill  <<<N_EDGES / 256, 256, 0, stream>>>(ei, deg, cursor, csr);
    k_gather1<<<N_NODES / 4, 256, 0, stream>>>(x, deg, csr, hpre);
    k_mlp1  <<<N_NODES / 32, 256, 0, stream>>>(hpre, W1a, b1a, W1b, b1b);
    k_gemm_y<<<N_NODES / 32, 256, 0, stream>>>(hpre, W2a, y);
    k_gather2<<<N_NODES / 4, 256, 0, stream>>>(y, deg, csr, b2a, W2b, b2b, out);
}

// Round 2
// 670.184 us; speedup vs baseline: 1.0830x; 1.0830x over previous
//
#include <hip/hip_runtime.h>

#define N_NODES 100000
#define N_EDGES 1600000
#define DIM 128
#define NC 40

typedef short bf16x8 __attribute__((ext_vector_type(8)));
typedef float f32x4 __attribute__((ext_vector_type(4)));

__device__ __forceinline__ ushort f2bf(float x) {
    unsigned u = __float_as_uint(x);
    return (ushort)((u + 0x7FFF + ((u >> 16) & 1)) >> 16);
}
__device__ __forceinline__ float bf2f(ushort h) {
    return __uint_as_float(((unsigned)h) << 16);
}

// ---------------- CSR build ----------------
__global__ __launch_bounds__(256) void k_hist(const int2* __restrict__ ei, int* __restrict__ deg) {
    int i = blockIdx.x * 256 + threadIdx.x;
    if (i < N_EDGES) {
        int2 e = ei[i];
        atomicAdd(&deg[e.y + 1], 1);
    }
}

#define SCAN_N (N_NODES + 1)
#define SCAN_T 256
#define SCAN_PER 32
#define SCAN_CHUNK (SCAN_T * SCAN_PER)                      // 8192
#define SCAN_NB ((SCAN_N + SCAN_CHUNK - 1) / SCAN_CHUNK)    // 13

__global__ __launch_bounds__(SCAN_T) void k_scan1(int* __restrict__ a, int* __restrict__ bsums) {
    __shared__ int wtot[SCAN_T / 64];
    int t = threadIdx.x, lane = t & 63, wid = t >> 6;
    int base = blockIdx.x * SCAN_CHUNK + t * SCAN_PER;
    int v[SCAN_PER];
    int run = 0;
    #pragma unroll
    for (int j = 0; j < SCAN_PER; ++j) {
        int idx = base + j;
        int x = (idx < SCAN_N) ? a[idx] : 0;
        run += x;
        v[j] = run;
    }
    int incl = run;
    #pragma unroll
    for (int d = 1; d < 64; d <<= 1) {
        int u = __shfl_up(incl, d, 64);
        if (lane >= d) incl += u;
    }
    if (lane == 63) wtot[wid] = incl;
    __syncthreads();
    int add = incl - run;
    for (int w = 0; w < wid; ++w) add += wtot[w];
    #pragma unroll
    for (int j = 0; j < SCAN_PER; ++j) {
        int idx = base + j;
        if (idx < SCAN_N) a[idx] = v[j] + add;
    }
    if (t == 0) {
        int tot = 0;
        for (int w = 0; w < SCAN_T / 64; ++w) tot += wtot[w];
        bsums[blockIdx.x] = tot;
    }
}

__global__ __launch_bounds__(SCAN_T) void k_scan2(int* __restrict__ a, const int* __restrict__ bsums) {
    int off = 0;
    for (int i = 0; i < (int)blockIdx.x; ++i) off += bsums[i];
    int base = blockIdx.x * SCAN_CHUNK + threadIdx.x;
    #pragma unroll
    for (int j = 0; j < SCAN_PER; ++j) {
        int idx = base + j * SCAN_T;
        if (idx < SCAN_N) a[idx] += off;
    }
}

__global__ __launch_bounds__(256) void k_fill(const int2* __restrict__ ei, const int* __restrict__ row_ptr,
                                              int* __restrict__ cursor, int* __restrict__ csr_src) {
    int i = blockIdx.x * 256 + threadIdx.x;
    if (i < N_EDGES) {
        int2 e = ei[i];
        int p = atomicAdd(&cursor[e.y], 1);
        csr_src[row_ptr[e.y] + p] = e.x;
    }
}

// ---------------- pack W (128x128) into MFMA B-fragment order, bf16 hi/lo split ----------------
// chunk = (kt*8 + nt)*64 + lane; element j: k = 32*kt + (lane>>4)*8 + j, n = 16*nt + (lane&15)
__global__ __launch_bounds__(256) void k_packW(const float* __restrict__ W,
                                               ushort* __restrict__ hi, ushort* __restrict__ lo) {
    int t = blockIdx.x * 256 + threadIdx.x;   // 0..2047
    int l = t & 63;
    int nt = (t >> 6) & 7;
    int kt = t >> 9;
    int n = nt * 16 + (l & 15);
    int kbase = kt * 32 + (l >> 4) * 8;
    size_t off = (size_t)t * 8;
    #pragma unroll
    for (int j = 0; j < 8; ++j) {
        float wv = W[(size_t)(kbase + j) * DIM + n];
        ushort h = f2bf(wv);
        hi[off + j] = h;
        lo[off + j] = f2bf(wv - bf2f(h));
    }
}

// ---------------- layer 1 aggregation: hpre = x + segsum(x[src]) ----------------
__global__ __launch_bounds__(256) void k_gather1(const float* __restrict__ x, const int* __restrict__ row_ptr,
                                                 const int* __restrict__ csr_src, float* __restrict__ hpre) {
    int lane = threadIdx.x & 63, wid = threadIdx.x >> 6;
    int n = blockIdx.x * 4 + wid;
    float2 acc = ((const float2*)(x + (size_t)n * DIM))[lane];
    int i = row_ptr[n], e = row_ptr[n + 1];
    for (; i + 4 <= e; i += 4) {
        int s0 = csr_src[i], s1 = csr_src[i + 1], s2 = csr_src[i + 2], s3 = csr_src[i + 3];
        float2 v0 = ((const float2*)(x + (size_t)s0 * DIM))[lane];
        float2 v1 = ((const float2*)(x + (size_t)s1 * DIM))[lane];
        float2 v2 = ((const float2*)(x + (size_t)s2 * DIM))[lane];
        float2 v3 = ((const float2*)(x + (size_t)s3 * DIM))[lane];
        acc.x += (v0.x + v1.x) + (v2.x + v3.x);
        acc.y += (v0.y + v1.y) + (v2.y + v3.y);
    }
    for (; i < e; ++i) {
        int s = csr_src[i];
        float2 v = ((const float2*)(x + (size_t)s * DIM))[lane];
        acc.x += v.x; acc.y += v.y;
    }
    ((float2*)(hpre + (size_t)n * DIM))[lane] = acc;
}

// ---------------- layer 1 MLP via bf16-split MFMA (in-place on hx) ----------------
// x2 = relu(relu(h@W1a+b1a)@W1b+b1b), fp32 acc; A*B ~= hi*hi + lo*hi + hi*lo
__global__ __launch_bounds__(256) void k_mlp1_mfma(float* __restrict__ hx,
    const ushort* __restrict__ Wahi, const ushort* __restrict__ Walo,
    const ushort* __restrict__ Wbhi, const ushort* __restrict__ Wblo,
    const float* __restrict__ b1a, const float* __restrict__ b1b) {
    __shared__ ushort Ahi[64][136];   // +8 pad: 272B row stride, 16B-aligned frag reads
    __shared__ ushort Alo[64][136];
    __shared__ ushort Hhi[64][136];
    __shared__ ushort Hlo[64][136];
    int t = threadIdx.x;
    size_t row0 = (size_t)blockIdx.x * 64;

    // stage x tile -> bf16 hi/lo in LDS
    for (int i = t; i < 64 * 32; i += 256) {
        int r = i >> 5, c4 = i & 31;
        size_t g = row0 + r;
        if (g >= N_NODES) g = N_NODES - 1;   // clamp: reads stay in-bounds, store is guarded
        float4 v = ((const float4*)(hx + g * DIM))[c4];
        ushort4 h, lo;
        h.x = f2bf(v.x); lo.x = f2bf(v.x - bf2f(h.x));
        h.y = f2bf(v.y); lo.y = f2bf(v.y - bf2f(h.y));
        h.z = f2bf(v.z); lo.z = f2bf(v.z - bf2f(h.z));
        h.w = f2bf(v.w); lo.w = f2bf(v.w - bf2f(h.w));
        *(ushort4*)&Ahi[r][c4 * 4] = h;
        *(ushort4*)&Alo[r][c4 * 4] = lo;
    }
    __syncthreads();

    int w = t >> 6, l = t & 63;
    int arow = 16 * w + (l & 15);
    int kq = (l >> 4) * 8;
    bf16x8 ah[4], al[4];
    f32x4 acc[8];

    // ---- GEMM1: h @ W1a + b1a, relu ----
    #pragma unroll
    for (int kt = 0; kt < 4; ++kt) {
        ah[kt] = *(const bf16x8*)&Ahi[arow][kt * 32 + kq];
        al[kt] = *(const bf16x8*)&Alo[arow][kt * 32 + kq];
    }
    #pragma unroll
    for (int nt = 0; nt < 8; ++nt) {
        float b = b1a[nt * 16 + (l & 15)];
        acc[nt] = (f32x4){b, b, b, b};
    }
    #pragma unroll
    for (int nt = 0; nt < 8; ++nt) {
        #pragma unroll
        for (int kt = 0; kt < 4; ++kt) {
            bf16x8 bh = *(const bf16x8*)(Wahi + (size_t)(((kt << 3) + nt) * 64 + l) * 8);
            bf16x8 bl = *(const bf16x8*)(Walo + (size_t)(((kt << 3) + nt) * 64 + l) * 8);
            acc[nt] = __builtin_amdgcn_mfma_f32_16x16x32_bf16(ah[kt], bh, acc[nt], 0, 0, 0);
            acc[nt] = __builtin_amdgcn_mfma_f32_16x16x32_bf16(al[kt], bh, acc[nt], 0, 0, 0);
            acc[nt] = __builtin_amdgcn_mfma_f32_16x16x32_bf16(ah[kt], bl, acc[nt], 0, 0, 0);
        }
    }
    // relu + split -> H LDS (C layout: row=(l>>4)*4+reg, col=16*nt+(l&15))
    #pragma unroll
    for (int nt = 0; nt < 8; ++nt) {
        #pragma unroll
        for (int r = 0; r < 4; ++r) {
            float v = fmaxf(acc[nt][r], 0.f);
            ushort h = f2bf(v);
            int hr = 16 * w + (l >> 4) * 4 + r;
            int hc = nt * 16 + (l & 15);
            Hhi[hr][hc] = h;
            Hlo[hr][hc] = f2bf(v - bf2f(h));
        }
    }
    __syncthreads();

    // ---- GEMM2: h1 @ W1b + b1b, relu, store fp32 ----
    #pragma unroll
    for (int kt = 0; kt < 4; ++kt) {
        ah[kt] = *(const bf16x8*)&Hhi[arow][kt * 32 + kq];
        al[kt] = *(const bf16x8*)&Hlo[arow][kt * 32 + kq];
    }
    #pragma unroll
    for (int nt = 0; nt < 8; ++nt) {
        float b = b1b[nt * 16 + (l & 15)];
        acc[nt] = (f32x4){b, b, b, b};
    }
    #pragma unroll
    for (int nt = 0; nt < 8; ++nt) {
        #pragma unroll
        for (int kt = 0; kt < 4; ++kt) {
            bf16x8 bh = *(const bf16x8*)(Wbhi + (size_t)(((kt << 3) + nt) * 64 + l) * 8);
            bf16x8 bl = *(const bf16x8*)(Wblo + (size_t)(((kt << 3) + nt) * 64 + l) * 8);
            acc[nt] = __builtin_amdgcn_mfma_f32_16x16x32_bf16(ah[kt], bh, acc[nt], 0, 0, 0);
            acc[nt] = __builtin_amdgcn_mfma_f32_16x16x32_bf16(al[kt], bh, acc[nt], 0, 0, 0);
            acc[nt] = __builtin_amdgcn_mfma_f32_16x16x32_bf16(ah[kt], bl, acc[nt], 0, 0, 0);
        }
    }
    #pragma unroll
    for (int nt = 0; nt < 8; ++nt) {
        #pragma unroll
        for (int r = 0; r < 4; ++r) {
            float v = fmaxf(acc[nt][r], 0.f);
            size_t gr = row0 + 16 * w + (l >> 4) * 4 + r;
            if (gr < N_NODES) hx[gr * DIM + nt * 16 + (l & 15)] = v;
        }
    }
}

// ---------------- y = x2 @ W2a (bias deferred; aggregation pushed past the matmul) ----------------
__global__ __launch_bounds__(256) void k_gemm_y(const float* __restrict__ x2, const float* __restrict__ W2a,
                                                float* __restrict__ y) {
    __shared__ float in_t[32][DIM + 4];
    int t = threadIdx.x;
    size_t row0 = (size_t)blockIdx.x * 32;
    for (int i = t; i < 32 * (DIM / 4); i += 256) {
        int r = i >> 5, c4 = i & 31;
        ((float4*)in_t[r])[c4] = ((const float4*)(x2 + (row0 + r) * DIM))[c4];
    }
    __syncthreads();
    int r = t >> 3, c0 = (t & 7) * 5;
    float acc[5] = {0.f, 0.f, 0.f, 0.f, 0.f};
    #pragma unroll 4
    for (int k = 0; k < DIM; ++k) {
        float a = in_t[r][k];
        #pragma unroll
        for (int j = 0; j < 5; ++j) acc[j] += a * W2a[(size_t)k * NC + c0 + j];
    }
    #pragma unroll
    for (int j = 0; j < 5; ++j) y[(row0 + r) * NC + c0 + j] = acc[j];
}

// ---------------- z = y + segsum(y[src]); h2 = relu(z+b2a); out = softmax(h2@W2b+b2b) ----------------
__global__ __launch_bounds__(256) void k_gather2(const float* __restrict__ y, const int* __restrict__ row_ptr,
                                                 const int* __restrict__ csr_src, const float* __restrict__ b2a,
                                                 const float* __restrict__ W2b, const float* __restrict__ b2b,
                                                 float* __restrict__ out) {
    __shared__ float h2s[4][NC];
    int lane = threadIdx.x & 63, wid = threadIdx.x >> 6;
    int n = blockIdx.x * 4 + wid;
    float acc = 0.f;
    if (lane < NC) acc = y[(size_t)n * NC + lane];
    int i = row_ptr[n], e = row_ptr[n + 1];
    for (; i + 4 <= e; i += 4) {
        int s0 = csr_src[i], s1 = csr_src[i + 1], s2 = csr_src[i + 2], s3 = csr_src[i + 3];
        if (lane < NC) {
            acc += (y[(size_t)s0 * NC + lane] + y[(size_t)s1 * NC + lane]) +
                   (y[(size_t)s2 * NC + lane] + y[(size_t)s3 * NC + lane]);
        }
    }
    for (; i < e; ++i) {
        int s = csr_src[i];
        if (lane < NC) acc += y[(size_t)s * NC + lane];
    }
    if (lane < NC) h2s[wid][lane] = fmaxf(acc + b2a[lane], 0.f);
    __syncthreads();
    float logit = -__builtin_inff();
    if (lane < NC) {
        float a = b2b[lane];
        #pragma unroll 4
        for (int k = 0; k < NC; ++k) a += h2s[wid][k] * W2b[k * NC + lane];
        logit = a;
    }
    float m = logit;
    #pragma unroll
    for (int d = 32; d >= 1; d >>= 1) m = fmaxf(m, __shfl_xor(m, d, 64));
    float ev = (lane < NC) ? __expf(logit - m) : 0.f;
    float s = ev;
    #pragma unroll
    for (int d = 32; d >= 1; d >>= 1) s += __shfl_xor(s, d, 64);
    if (lane < NC) out[(size_t)n * NC + lane] = ev / s;
}

extern "C" void kernel_launch(void* const* d_in, const int* in_sizes, int n_in,
                              void* d_out, int out_size, void* d_ws, size_t ws_size,
                              hipStream_t stream) {
    const float* x   = (const float*)d_in[0];
    const int2*  ei  = (const int2*)d_in[1];
    const float* W1a = (const float*)d_in[2];
    const float* b1a = (const float*)d_in[3];
    const float* W1b = (const float*)d_in[4];
    const float* b1b = (const float*)d_in[5];
    const float* W2a = (const float*)d_in[6];
    const float* b2a = (const float*)d_in[7];
    const float* W2b = (const float*)d_in[8];
    const float* b2b = (const float*)d_in[9];
    float* out = (float*)d_out;

    char* w = (char*)d_ws;
    int*   deg    = (int*)(w + 0);           // 100001 ints, becomes row_ptr after scan
    int*   cursor = (int*)(w + 400004);      // 100000 ints (dead after k_fill)
    int*   bsums  = (int*)(w + 800004);      // 16 ints
    int*   csr    = (int*)(w + 800128);      // 1.6M ints (src ids grouped by dst)
    float* hpre   = (float*)(w + 7200256);   // 100000x128 (hpre -> x2 in-place)
    float* y      = (float*)(w + 58400256);  // 100000x40
    // packed W fragments overlay the (dead-after-fill) cursor region: 4 x 32KB
    ushort* Wahi = (ushort*)(w + 400016);
    ushort* Walo = (ushort*)(w + 432784);
    ushort* Wbhi = (ushort*)(w + 465552);
    ushort* Wblo = (ushort*)(w + 498320);
    // total ws needed: 74,400,256 bytes

    hipMemsetAsync(w, 0, 800068, stream);  // zero deg + cursor (+bsums)
    k_hist  <<<N_EDGES / 256, 256, 0, stream>>>(ei, deg);
    k_scan1 <<<SCAN_NB, SCAN_T, 0, stream>>>(deg, bsums);
    k_scan2 <<<SCAN_NB, SCAN_T, 0, stream>>>(deg, bsums);
    k_fill  <<<N_EDGES / 256, 256, 0, stream>>>(ei, deg, cursor, csr);
    k_packW <<<8, 256, 0, stream>>>(W1a, Wahi, Walo);
    k_packW <<<8, 256, 0, stream>>>(W1b, Wbhi, Wblo);
    k_gather1<<<N_NODES / 4, 256, 0, stream>>>(x, deg, csr, hpre);
    k_mlp1_mfma<<<(N_NODES + 63) / 64, 256, 0, stream>>>(hpre, Wahi, Walo, Wbhi, Wblo, b1a, b1b);
    k_gemm_y<<<N_NODES / 32, 256, 0, stream>>>(hpre, W2a, y);
    k_gather2<<<N_NODES / 4, 256, 0, stream>>>(y, deg, csr, b2a, W2b, b2b, out);
}

// Round 3
// 503.494 us; speedup vs baseline: 1.4416x; 1.3311x over previous
//
#include <hip/hip_runtime.h>
#include <hip/hip_fp16.h>

#define N_NODES 100000
#define N_EDGES 1600000
#define DIM 128
#define NC 40

typedef _Float16 f16x8 __attribute__((ext_vector_type(8)));
typedef float f32x4 __attribute__((ext_vector_type(4)));

// ---------------- CSR hist + x -> fp16 convert (fused) ----------------
__global__ __launch_bounds__(256) void k_hist_cvt(const int2* __restrict__ ei, int* __restrict__ deg,
                                                  const float* __restrict__ x, __half* __restrict__ xh) {
    int i = blockIdx.x * 256 + threadIdx.x;       // 6250*256 == N_EDGES exactly
    int2 e = ei[i];
    atomicAdd(&deg[e.y + 1], 1);
    // convert 8 floats -> 8 halves; 6250*256*8 == N_NODES*DIM exactly
    float4 v0 = ((const float4*)x)[(size_t)i * 2];
    float4 v1 = ((const float4*)x)[(size_t)i * 2 + 1];
    __half2 h01 = __float22half2_rn(make_float2(v0.x, v0.y));
    __half2 h23 = __float22half2_rn(make_float2(v0.z, v0.w));
    __half2 h45 = __float22half2_rn(make_float2(v1.x, v1.y));
    __half2 h67 = __float22half2_rn(make_float2(v1.z, v1.w));
    uint4 o;
    o.x = *(unsigned*)&h01; o.y = *(unsigned*)&h23;
    o.z = *(unsigned*)&h45; o.w = *(unsigned*)&h67;
    ((uint4*)xh)[i] = o;
}

#define SCAN_N (N_NODES + 1)
#define SCAN_T 256
#define SCAN_PER 32
#define SCAN_CHUNK (SCAN_T * SCAN_PER)                      // 8192
#define SCAN_NB ((SCAN_N + SCAN_CHUNK - 1) / SCAN_CHUNK)    // 13

__global__ __launch_bounds__(SCAN_T) void k_scan1(int* __restrict__ a, int* __restrict__ bsums) {
    __shared__ int wtot[SCAN_T / 64];
    int t = threadIdx.x, lane = t & 63, wid = t >> 6;
    int base = blockIdx.x * SCAN_CHUNK + t * SCAN_PER;
    int v[SCAN_PER];
    int run = 0;
    #pragma unroll
    for (int j = 0; j < SCAN_PER; ++j) {
        int idx = base + j;
        int x = (idx < SCAN_N) ? a[idx] : 0;
        run += x;
        v[j] = run;
    }
    int incl = run;
    #pragma unroll
    for (int d = 1; d < 64; d <<= 1) {
        int u = __shfl_up(incl, d, 64);
        if (lane >= d) incl += u;
    }
    if (lane == 63) wtot[wid] = incl;
    __syncthreads();
    int add = incl - run;
    for (int w = 0; w < wid; ++w) add += wtot[w];
    #pragma unroll
    for (int j = 0; j < SCAN_PER; ++j) {
        int idx = base + j;
        if (idx < SCAN_N) a[idx] = v[j] + add;
    }
    if (t == 0) {
        int tot = 0;
        for (int w = 0; w < SCAN_T / 64; ++w) tot += wtot[w];
        bsums[blockIdx.x] = tot;
    }
}

__global__ __launch_bounds__(SCAN_T) void k_scan2(int* __restrict__ a, const int* __restrict__ bsums) {
    int off = 0;
    for (int i = 0; i < (int)blockIdx.x; ++i) off += bsums[i];
    int base = blockIdx.x * SCAN_CHUNK + threadIdx.x;
    #pragma unroll
    for (int j = 0; j < SCAN_PER; ++j) {
        int idx = base + j * SCAN_T;
        if (idx < SCAN_N) a[idx] += off;
    }
}

__global__ __launch_bounds__(256) void k_fill(const int2* __restrict__ ei, const int* __restrict__ row_ptr,
                                              int* __restrict__ cursor, int* __restrict__ csr_src) {
    int i = blockIdx.x * 256 + threadIdx.x;
    if (i < N_EDGES) {
        int2 e = ei[i];
        int p = atomicAdd(&cursor[e.y], 1);
        csr_src[row_ptr[e.y] + p] = e.x;
    }
}

// ---------------- pack W1a/W1b (128x128) and W2a (128x40->48) into fp16 MFMA B-frags ----------------
// frag chunk c holds: k = 32*kt + (lane>>4)*8 + j, n = 16*nt + (lane&15); c = kt*NT + nt
__global__ __launch_bounds__(256) void k_pack(const float* __restrict__ W1a, const float* __restrict__ W1b,
                                              const float* __restrict__ W2a,
                                              _Float16* __restrict__ Pa, _Float16* __restrict__ Pb,
                                              _Float16* __restrict__ Pc) {
    int bid = blockIdx.x, tid = threadIdx.x;
    if (bid < 16) {
        const float* W = (bid < 8) ? W1a : W1b;
        _Float16* P = (bid < 8) ? Pa : Pb;
        int t = (bid & 7) * 256 + tid;          // 0..2047
        int l = t & 63, nt = (t >> 6) & 7, kt = t >> 9;
        int n = nt * 16 + (l & 15);
        int kb = kt * 32 + (l >> 4) * 8;
        #pragma unroll
        for (int j = 0; j < 8; ++j)
            P[(size_t)t * 8 + j] = (_Float16)W[(size_t)(kb + j) * DIM + n];
    } else {
        int t = (bid - 16) * 256 + tid;         // 0..767
        if (t < 768) {
            int l = t & 63, u = t >> 6;          // u = kt*3 + nt
            int nt = u % 3, kt = u / 3;
            int n = nt * 16 + (l & 15);
            int kb = kt * 32 + (l >> 4) * 8;
            #pragma unroll
            for (int j = 0; j < 8; ++j) {
                float wv = (n < NC) ? W2a[(size_t)(kb + j) * NC + n] : 0.f;
                Pc[(size_t)t * 8 + j] = (_Float16)wv;
            }
        }
    }
}

// ---------------- layer 1 aggregation (fp16 payload, fp32 accum): hp = x + segsum(x[src]) ----------------
__global__ __launch_bounds__(256) void k_gather1(const __half2* __restrict__ xh2, const int* __restrict__ row_ptr,
                                                 const int* __restrict__ csr_src, __half2* __restrict__ hp2) {
    int lane = threadIdx.x & 63, wid = threadIdx.x >> 6;
    int n = blockIdx.x * 4 + wid;
    float2 acc = __half22float2(xh2[(size_t)n * 64 + lane]);
    int i = row_ptr[n], e = row_ptr[n + 1];
    for (; i + 4 <= e; i += 4) {
        int s0 = csr_src[i], s1 = csr_src[i + 1], s2 = csr_src[i + 2], s3 = csr_src[i + 3];
        float2 v0 = __half22float2(xh2[(size_t)s0 * 64 + lane]);
        float2 v1 = __half22float2(xh2[(size_t)s1 * 64 + lane]);
        float2 v2 = __half22float2(xh2[(size_t)s2 * 64 + lane]);
        float2 v3 = __half22float2(xh2[(size_t)s3 * 64 + lane]);
        acc.x += (v0.x + v1.x) + (v2.x + v3.x);
        acc.y += (v0.y + v1.y) + (v2.y + v3.y);
    }
    for (; i < e; ++i) {
        int s = csr_src[i];
        float2 v = __half22float2(xh2[(size_t)s * 64 + lane]);
        acc.x += v.x; acc.y += v.y;
    }
    hp2[(size_t)n * 64 + lane] = __float22half2_rn(acc);
}

// ---------------- fused MLP via fp16 MFMA: y = relu(relu(hp@W1a+b1a)@W1b+b1b) @ W2a ----------------
__global__ __launch_bounds__(256) void k_mlp(const __half* __restrict__ hp,
    const _Float16* __restrict__ Pa, const _Float16* __restrict__ Pb, const _Float16* __restrict__ Pc,
    const float* __restrict__ b1a, const float* __restrict__ b1b, __half* __restrict__ y) {
    __shared__ _Float16 A[64][136];   // +8 pad (16B): aligned frag reads
    __shared__ _Float16 H[64][136];
    int t = threadIdx.x;
    size_t row0 = (size_t)blockIdx.x * 64;

    // stage hp tile (fp16, direct copy)
    for (int i = t; i < 1024; i += 256) {
        int r = i >> 4, c = i & 15;
        size_t g = row0 + r;
        if (g >= N_NODES) g = N_NODES - 1;    // clamped read; stores guarded below
        uint4 v = ((const uint4*)(hp + g * DIM))[c];
        *(uint4*)&A[r][c * 8] = v;
    }
    __syncthreads();

    int w = t >> 6, l = t & 63;
    int arow = 16 * w + (l & 15);
    int kq = (l >> 4) * 8;
    int crow = 16 * w + (l >> 4) * 4;          // C-layout row base
    int ccol = l & 15;
    f16x8 af[4];
    f32x4 acc[8];

    // ---- GEMM1: A @ W1a + b1a, relu -> H ----
    #pragma unroll
    for (int kt = 0; kt < 4; ++kt) af[kt] = *(const f16x8*)&A[arow][kt * 32 + kq];
    #pragma unroll
    for (int nt = 0; nt < 8; ++nt) {
        float b = b1a[nt * 16 + ccol];
        acc[nt] = (f32x4){b, b, b, b};
    }
    #pragma unroll
    for (int nt = 0; nt < 8; ++nt)
        #pragma unroll
        for (int kt = 0; kt < 4; ++kt) {
            f16x8 bf = *(const f16x8*)(Pc + 0 * 1 + (size_t)0 + ((size_t)((kt << 3) + nt) * 64 + l) * 8 - (size_t)((kt << 3) + nt) * 64 * 8 + ((size_t)((kt << 3) + nt) * 64 + l) * 8); // placeholder removed below
            (void)bf;
        }
    // (real loop)
    #pragma unroll
    for (int nt = 0; nt < 8; ++nt)
        #pragma unroll
        for (int kt = 0; kt < 4; ++kt) {
            f16x8 bf = *(const f16x8*)(Pa + ((size_t)((kt << 3) + nt) * 64 + l) * 8);
            acc[nt] = __builtin_amdgcn_mfma_f32_16x16x32_f16(af[kt], bf, acc[nt], 0, 0, 0);
        }
    #pragma unroll
    for (int nt = 0; nt < 8; ++nt)
        #pragma unroll
        for (int r = 0; r < 4; ++r)
            H[crow + r][nt * 16 + ccol] = (_Float16)fmaxf(acc[nt][r], 0.f);
    __syncthreads();

    // ---- GEMM2: H @ W1b + b1b, relu -> A (A fully consumed before prior sync) ----
    #pragma unroll
    for (int kt = 0; kt < 4; ++kt) af[kt] = *(const f16x8*)&H[arow][kt * 32 + kq];
    #pragma unroll
    for (int nt = 0; nt < 8; ++nt) {
        float b = b1b[nt * 16 + ccol];
        acc[nt] = (f32x4){b, b, b, b};
    }
    #pragma unroll
    for (int nt = 0; nt < 8; ++nt)
        #pragma unroll
        for (int kt = 0; kt < 4; ++kt) {
            f16x8 bf = *(const f16x8*)(Pb + ((size_t)((kt << 3) + nt) * 64 + l) * 8);
            acc[nt] = __builtin_amdgcn_mfma_f32_16x16x32_f16(af[kt], bf, acc[nt], 0, 0, 0);
        }
    #pragma unroll
    for (int nt = 0; nt < 8; ++nt)
        #pragma unroll
        for (int r = 0; r < 4; ++r)
            A[crow + r][nt * 16 + ccol] = (_Float16)fmaxf(acc[nt][r], 0.f);
    __syncthreads();

    // ---- GEMM3: x2 @ W2a (bias deferred past aggregation) -> y fp16 ----
    #pragma unroll
    for (int kt = 0; kt < 4; ++kt) af[kt] = *(const f16x8*)&A[arow][kt * 32 + kq];
    f32x4 ya[3];
    #pragma unroll
    for (int nt = 0; nt < 3; ++nt) ya[nt] = (f32x4){0.f, 0.f, 0.f, 0.f};
    #pragma unroll
    for (int nt = 0; nt < 3; ++nt)
        #pragma unroll
        for (int kt = 0; kt < 4; ++kt) {
            f16x8 bf = *(const f16x8*)(Pc + ((size_t)(kt * 3 + nt) * 64 + l) * 8);
            ya[nt] = __builtin_amdgcn_mfma_f32_16x16x32_f16(af[kt], bf, ya[nt], 0, 0, 0);
        }
    #pragma unroll
    for (int nt = 0; nt < 3; ++nt) {
        int col = nt * 16 + ccol;
        if (col < NC) {
            #pragma unroll
            for (int r = 0; r < 4; ++r) {
                size_t gr = row0 + crow + r;
                if (gr < N_NODES) y[gr * NC + col] = __float2half(ya[nt][r]);
            }
        }
    }
}

// ---------------- z = y + segsum(y[src]); h2 = relu(z+b2a); out = softmax(h2@W2b+b2b) ----------------
__global__ __launch_bounds__(256) void k_gather2(const __half* __restrict__ y, const int* __restrict__ row_ptr,
                                                 const int* __restrict__ csr_src, const float* __restrict__ b2a,
                                                 const float* __restrict__ W2b, const float* __restrict__ b2b,
                                                 float* __restrict__ out) {
    __shared__ float h2s[4][NC];
    int lane = threadIdx.x & 63, wid = threadIdx.x >> 6;
    int n = blockIdx.x * 4 + wid;
    float acc = 0.f;
    if (lane < NC) acc = __half2float(y[(size_t)n * NC + lane]);
    int i = row_ptr[n], e = row_ptr[n + 1];
    for (; i + 4 <= e; i += 4) {
        int s0 = csr_src[i], s1 = csr_src[i + 1], s2 = csr_src[i + 2], s3 = csr_src[i + 3];
        if (lane < NC) {
            acc += (__half2float(y[(size_t)s0 * NC + lane]) + __half2float(y[(size_t)s1 * NC + lane])) +
                   (__half2float(y[(size_t)s2 * NC + lane]) + __half2float(y[(size_t)s3 * NC + lane]));
        }
    }
    for (; i < e; ++i) {
        int s = csr_src[i];
        if (lane < NC) acc += __half2float(y[(size_t)s * NC + lane]);
    }
    if (lane < NC) h2s[wid][lane] = fmaxf(acc + b2a[lane], 0.f);
    __syncthreads();
    float logit = -__builtin_inff();
    if (lane < NC) {
        float a = b2b[lane];
        #pragma unroll 4
        for (int k = 0; k < NC; ++k) a += h2s[wid][k] * W2b[k * NC + lane];
        logit = a;
    }
    float m = logit;
    #pragma unroll
    for (int d = 32; d >= 1; d >>= 1) m = fmaxf(m, __shfl_xor(m, d, 64));
    float ev = (lane < NC) ? __expf(logit - m) : 0.f;
    float s = ev;
    #pragma unroll
    for (int d = 32; d >= 1; d >>= 1) s += __shfl_xor(s, d, 64);
    if (lane < NC) out[(size_t)n * NC + lane] = ev / s;
}

extern "C" void kernel_launch(void* const* d_in, const int* in_sizes, int n_in,
                              void* d_out, int out_size, void* d_ws, size_t ws_size,
                              hipStream_t stream) {
    const float* x   = (const float*)d_in[0];
    const int2*  ei  = (const int2*)d_in[1];
    const float* W1a = (const float*)d_in[2];
    const float* b1a = (const float*)d_in[3];
    const float* W1b = (const float*)d_in[4];
    const float* b1b = (const float*)d_in[5];
    const float* W2a = (const float*)d_in[6];
    const float* b2a = (const float*)d_in[7];
    const float* W2b = (const float*)d_in[8];
    const float* b2b = (const float*)d_in[9];
    float* out = (float*)d_out;

    char* w = (char*)d_ws;
    int*    deg    = (int*)(w + 0);           // 100001 ints -> row_ptr after scan
    int*    cursor = (int*)(w + 400128);      // 100000 ints
    int*    bsums  = (int*)(w + 800128);      // 16 ints
    int*    csr    = (int*)(w + 800192);      // 1.6M ints
    __half* xh     = (__half*)(w + 7200256);  // 100000x128 fp16
    __half* hp     = (__half*)(w + 32800256); // 100000x128 fp16 (agg result)
    __half* y      = (__half*)(w + 58400256); // 100000x40 fp16
    _Float16* Pa   = (_Float16*)(w + 66400256); // 32KB W1a frags
    _Float16* Pb   = (_Float16*)(w + 66433024); // 32KB W1b frags
    _Float16* Pc   = (_Float16*)(w + 66465792); // 12KB W2a frags (padded to 48 cols)
    // total ws needed: 66,478,080 bytes

    hipMemsetAsync(w, 0, 800192, stream);  // zero deg + cursor + bsums
    k_hist_cvt<<<N_EDGES / 256, 256, 0, stream>>>(ei, deg, x, xh);
    k_scan1   <<<SCAN_NB, SCAN_T, 0, stream>>>(deg, bsums);
    k_scan2   <<<SCAN_NB, SCAN_T, 0, stream>>>(deg, bsums);
    k_fill    <<<N_EDGES / 256, 256, 0, stream>>>(ei, deg, cursor, csr);
    k_pack    <<<19, 256, 0, stream>>>(W1a, W1b, W2a, Pa, Pb, Pc);
    k_gather1 <<<N_NODES / 4, 256, 0, stream>>>((const __half2*)xh, deg, csr, (__half2*)hp);
    k_mlp     <<<(N_NODES + 63) / 64, 256, 0, stream>>>(hp, Pa, Pb, Pc, b1a, b1b, y);
    k_gather2 <<<N_NODES / 4, 256, 0, stream>>>(y, deg, csr, b2a, W2b, b2b, out);
}

// Round 4
// 489.908 us; speedup vs baseline: 1.4815x; 1.0277x over previous
//
#include <hip/hip_runtime.h>
#include <hip/hip_fp16.h>

#define N_NODES 100000
#define N_EDGES 1600000
#define DIM 128
#define NC 40

typedef _Float16 f16x8 __attribute__((ext_vector_type(8)));
typedef float f32x4 __attribute__((ext_vector_type(4)));

// ---------------- CSR hist + x -> fp16 convert (fused) ----------------
__global__ __launch_bounds__(256) void k_hist_cvt(const int2* __restrict__ ei, int* __restrict__ deg,
                                                  const float* __restrict__ x, __half* __restrict__ xh) {
    int i = blockIdx.x * 256 + threadIdx.x;       // 6250*256 == N_EDGES exactly
    int2 e = ei[i];
    atomicAdd(&deg[e.y + 1], 1);
    // convert 8 floats -> 8 halves; 6250*256*8 == N_NODES*DIM exactly
    float4 v0 = ((const float4*)x)[(size_t)i * 2];
    float4 v1 = ((const float4*)x)[(size_t)i * 2 + 1];
    __half2 h01 = __float22half2_rn(make_float2(v0.x, v0.y));
    __half2 h23 = __float22half2_rn(make_float2(v0.z, v0.w));
    __half2 h45 = __float22half2_rn(make_float2(v1.x, v1.y));
    __half2 h67 = __float22half2_rn(make_float2(v1.z, v1.w));
    uint4 o;
    o.x = *(unsigned*)&h01; o.y = *(unsigned*)&h23;
    o.z = *(unsigned*)&h45; o.w = *(unsigned*)&h67;
    ((uint4*)xh)[i] = o;
}

#define SCAN_N (N_NODES + 1)
#define SCAN_T 256
#define SCAN_PER 32
#define SCAN_CHUNK (SCAN_T * SCAN_PER)                      // 8192
#define SCAN_NB ((SCAN_N + SCAN_CHUNK - 1) / SCAN_CHUNK)    // 13

__global__ __launch_bounds__(SCAN_T) void k_scan1(int* __restrict__ a, int* __restrict__ bsums) {
    __shared__ int wtot[SCAN_T / 64];
    int t = threadIdx.x, lane = t & 63, wid = t >> 6;
    int base = blockIdx.x * SCAN_CHUNK + t * SCAN_PER;
    int v[SCAN_PER];
    int run = 0;
    #pragma unroll
    for (int j = 0; j < SCAN_PER; ++j) {
        int idx = base + j;
        int x = (idx < SCAN_N) ? a[idx] : 0;
        run += x;
        v[j] = run;
    }
    int incl = run;
    #pragma unroll
    for (int d = 1; d < 64; d <<= 1) {
        int u = __shfl_up(incl, d, 64);
        if (lane >= d) incl += u;
    }
    if (lane == 63) wtot[wid] = incl;
    __syncthreads();
    int add = incl - run;
    for (int w = 0; w < wid; ++w) add += wtot[w];
    #pragma unroll
    for (int j = 0; j < SCAN_PER; ++j) {
        int idx = base + j;
        if (idx < SCAN_N) a[idx] = v[j] + add;
    }
    if (t == 0) {
        int tot = 0;
        for (int w = 0; w < SCAN_T / 64; ++w) tot += wtot[w];
        bsums[blockIdx.x] = tot;
    }
}

// scan2 also mirrors the final row_ptr into cursor (so k_fill skips a row_ptr read)
__global__ __launch_bounds__(SCAN_T) void k_scan2(int* __restrict__ a, const int* __restrict__ bsums,
                                                  int* __restrict__ cursor) {
    int off = 0;
    for (int i = 0; i < (int)blockIdx.x; ++i) off += bsums[i];
    int base = blockIdx.x * SCAN_CHUNK + threadIdx.x;
    #pragma unroll
    for (int j = 0; j < SCAN_PER; ++j) {
        int idx = base + j * SCAN_T;
        if (idx < SCAN_N) {
            int v = a[idx] + off;
            a[idx] = v;
            if (idx < N_NODES) cursor[idx] = v;   // guard: cursor has N_NODES entries
        }
    }
}

__global__ __launch_bounds__(256) void k_fill(const int2* __restrict__ ei,
                                              int* __restrict__ cursor, int* __restrict__ csr_src) {
    int i = blockIdx.x * 256 + threadIdx.x;
    if (i < N_EDGES) {
        int2 e = ei[i];
        int p = atomicAdd(&cursor[e.y], 1);   // cursor pre-initialized to row_ptr
        csr_src[p] = e.x;
    }
}

// ---------------- pack W1a/W1b (128x128) and W2a (128x40->48) into fp16 MFMA B-frags ----------------
// frag chunk c holds: k = 32*kt + (lane>>4)*8 + j, n = 16*nt + (lane&15); c = kt*NT + nt
__global__ __launch_bounds__(256) void k_pack(const float* __restrict__ W1a, const float* __restrict__ W1b,
                                              const float* __restrict__ W2a,
                                              _Float16* __restrict__ Pa, _Float16* __restrict__ Pb,
                                              _Float16* __restrict__ Pc) {
    int bid = blockIdx.x, tid = threadIdx.x;
    if (bid < 16) {
        const float* W = (bid < 8) ? W1a : W1b;
        _Float16* P = (bid < 8) ? Pa : Pb;
        int t = (bid & 7) * 256 + tid;          // 0..2047
        int l = t & 63, nt = (t >> 6) & 7, kt = t >> 9;
        int n = nt * 16 + (l & 15);
        int kb = kt * 32 + (l >> 4) * 8;
        #pragma unroll
        for (int j = 0; j < 8; ++j)
            P[(size_t)t * 8 + j] = (_Float16)W[(size_t)(kb + j) * DIM + n];
    } else {
        int t = (bid - 16) * 256 + tid;         // 0..767
        if (t < 768) {
            int l = t & 63, u = t >> 6;          // u = kt*3 + nt
            int nt = u % 3, kt = u / 3;
            int n = nt * 16 + (l & 15);
            int kb = kt * 32 + (l >> 4) * 8;
            #pragma unroll
            for (int j = 0; j < 8; ++j) {
                float wv = (n < NC) ? W2a[(size_t)(kb + j) * NC + n] : 0.f;
                Pc[(size_t)t * 8 + j] = (_Float16)wv;
            }
        }
    }
}

// ---------------- layer 1 aggregation (fp16 payload, fp32 accum): hp = x + segsum(x[src]) ----------------
__global__ __launch_bounds__(256) void k_gather1(const __half2* __restrict__ xh2, const int* __restrict__ row_ptr,
                                                 const int* __restrict__ csr_src, __half2* __restrict__ hp2) {
    int lane = threadIdx.x & 63, wid = threadIdx.x >> 6;
    int n = blockIdx.x * 4 + wid;
    float2 acc = __half22float2(xh2[(size_t)n * 64 + lane]);
    int i = row_ptr[n], e = row_ptr[n + 1];
    for (; i + 8 <= e; i += 8) {
        float2 v[8];
        #pragma unroll
        for (int u = 0; u < 8; ++u) {
            int s = csr_src[i + u];
            v[u] = __half22float2(xh2[(size_t)s * 64 + lane]);
        }
        #pragma unroll
        for (int u = 0; u < 8; ++u) { acc.x += v[u].x; acc.y += v[u].y; }
    }
    for (; i < e; ++i) {
        int s = csr_src[i];
        float2 v = __half22float2(xh2[(size_t)s * 64 + lane]);
        acc.x += v.x; acc.y += v.y;
    }
    hp2[(size_t)n * 64 + lane] = __float22half2_rn(acc);
}

// ---------------- fused MLP via fp16 MFMA: y = relu(relu(hp@W1a+b1a)@W1b+b1b) @ W2a ----------------
__global__ __launch_bounds__(256) void k_mlp(const __half* __restrict__ hp,
    const _Float16* __restrict__ Pa, const _Float16* __restrict__ Pb, const _Float16* __restrict__ Pc,
    const float* __restrict__ b1a, const float* __restrict__ b1b, __half* __restrict__ y) {
    __shared__ _Float16 A[64][136];   // +8 pad (16B): aligned frag reads
    __shared__ _Float16 H[64][136];
    int t = threadIdx.x;
    size_t row0 = (size_t)blockIdx.x * 64;

    // stage hp tile (fp16, direct copy)
    for (int i = t; i < 1024; i += 256) {
        int r = i >> 4, c = i & 15;
        size_t g = row0 + r;
        if (g >= N_NODES) g = N_NODES - 1;    // clamped read; stores guarded below
        uint4 v = ((const uint4*)(hp + g * DIM))[c];
        *(uint4*)&A[r][c * 8] = v;
    }
    __syncthreads();

    int w = t >> 6, l = t & 63;
    int arow = 16 * w + (l & 15);
    int kq = (l >> 4) * 8;
    int crow = 16 * w + (l >> 4) * 4;          // C-layout row base
    int ccol = l & 15;
    f16x8 af[4];
    f32x4 acc[8];

    // ---- GEMM1: A @ W1a + b1a, relu -> H ----
    #pragma unroll
    for (int kt = 0; kt < 4; ++kt) af[kt] = *(const f16x8*)&A[arow][kt * 32 + kq];
    #pragma unroll
    for (int nt = 0; nt < 8; ++nt) {
        float b = b1a[nt * 16 + ccol];
        acc[nt] = (f32x4){b, b, b, b};
    }
    #pragma unroll
    for (int nt = 0; nt < 8; ++nt)
        #pragma unroll
        for (int kt = 0; kt < 4; ++kt) {
            f16x8 bf = *(const f16x8*)(Pa + ((size_t)((kt << 3) + nt) * 64 + l) * 8);
            acc[nt] = __builtin_amdgcn_mfma_f32_16x16x32_f16(af[kt], bf, acc[nt], 0, 0, 0);
        }
    #pragma unroll
    for (int nt = 0; nt < 8; ++nt)
        #pragma unroll
        for (int r = 0; r < 4; ++r)
            H[crow + r][nt * 16 + ccol] = (_Float16)fmaxf(acc[nt][r], 0.f);
    __syncthreads();

    // ---- GEMM2: H @ W1b + b1b, relu -> A (A fully consumed before prior sync) ----
    #pragma unroll
    for (int kt = 0; kt < 4; ++kt) af[kt] = *(const f16x8*)&H[arow][kt * 32 + kq];
    #pragma unroll
    for (int nt = 0; nt < 8; ++nt) {
        float b = b1b[nt * 16 + ccol];
        acc[nt] = (f32x4){b, b, b, b};
    }
    #pragma unroll
    for (int nt = 0; nt < 8; ++nt)
        #pragma unroll
        for (int kt = 0; kt < 4; ++kt) {
            f16x8 bf = *(const f16x8*)(Pb + ((size_t)((kt << 3) + nt) * 64 + l) * 8);
            acc[nt] = __builtin_amdgcn_mfma_f32_16x16x32_f16(af[kt], bf, acc[nt], 0, 0, 0);
        }
    #pragma unroll
    for (int nt = 0; nt < 8; ++nt)
        #pragma unroll
        for (int r = 0; r < 4; ++r)
            A[crow + r][nt * 16 + ccol] = (_Float16)fmaxf(acc[nt][r], 0.f);
    __syncthreads();

    // ---- GEMM3: x2 @ W2a (bias deferred past aggregation) -> y fp16 ----
    #pragma unroll
    for (int kt = 0; kt < 4; ++kt) af[kt] = *(const f16x8*)&A[arow][kt * 32 + kq];
    f32x4 ya[3];
    #pragma unroll
    for (int nt = 0; nt < 3; ++nt) ya[nt] = (f32x4){0.f, 0.f, 0.f, 0.f};
    #pragma unroll
    for (int nt = 0; nt < 3; ++nt)
        #pragma unroll
        for (int kt = 0; kt < 4; ++kt) {
            f16x8 bf = *(const f16x8*)(Pc + ((size_t)(kt * 3 + nt) * 64 + l) * 8);
            ya[nt] = __builtin_amdgcn_mfma_f32_16x16x32_f16(af[kt], bf, ya[nt], 0, 0, 0);
        }
    #pragma unroll
    for (int nt = 0; nt < 3; ++nt) {
        int col = nt * 16 + ccol;
        if (col < NC) {
            #pragma unroll
            for (int r = 0; r < 4; ++r) {
                size_t gr = row0 + crow + r;
                if (gr < N_NODES) y[gr * NC + col] = __float2half(ya[nt][r]);
            }
        }
    }
}

// ---------------- z = y + segsum(y[src]); h2 = relu(z+b2a); out = softmax(h2@W2b+b2b) ----------------
// Wide gather: y row = 40 halves = 5 x uint4 (16B-aligned). lane -> (edge group g=l/5, quarter j=l%5):
// 12 edges per VMEM instruction (60 active lanes x 16B).
__device__ __forceinline__ void acc_row8(float* acc, uint4 v) {
    __half2 h;
    float2 f;
    *(unsigned*)&h = v.x; f = __half22float2(h); acc[0] += f.x; acc[1] += f.y;
    *(unsigned*)&h = v.y; f = __half22float2(h); acc[2] += f.x; acc[3] += f.y;
    *(unsigned*)&h = v.z; f = __half22float2(h); acc[4] += f.x; acc[5] += f.y;
    *(unsigned*)&h = v.w; f = __half22float2(h); acc[6] += f.x; acc[7] += f.y;
}

__global__ __launch_bounds__(256) void k_gather2(const __half* __restrict__ y, const int* __restrict__ row_ptr,
                                                 const int* __restrict__ csr_src, const float* __restrict__ b2a,
                                                 const float* __restrict__ W2b, const float* __restrict__ b2b,
                                                 float* __restrict__ out) {
    __shared__ float h2s[4][NC];
    int l = threadIdx.x & 63, wid = threadIdx.x >> 6;
    int n = blockIdx.x * 4 + wid;
    int g = l / 5, j = l - g * 5;            // g in 0..12 (g==12 for lanes 60..63: inactive)
    const uint4* y4 = (const uint4*)y;

    float acc[8] = {0.f, 0.f, 0.f, 0.f, 0.f, 0.f, 0.f, 0.f};
    // self row via group 0
    if (l < 5) acc_row8(acc, y4[(size_t)n * 5 + j]);

    int i0 = row_ptr[n], e = row_ptr[n + 1];
    for (int i = i0; i < e; i += 12) {
        int idx = i + g;
        if (g < 12 && idx < e) {
            int s = csr_src[idx];
            acc_row8(acc, y4[(size_t)s * 5 + j]);
        }
    }
    // combine 12 groups -> group 0 (lanes 0..4)
    #pragma unroll
    for (int k = 0; k < 8; ++k) acc[k] += __shfl_down(acc[k], 30);   // g += 6  (valid g<6)
    #pragma unroll
    for (int k = 0; k < 8; ++k) acc[k] += __shfl_down(acc[k], 15);   // g += 3  (valid g<3)
    #pragma unroll
    for (int k = 0; k < 8; ++k) acc[k] += __shfl_down(acc[k], 5) + __shfl_down(acc[k], 10);

    if (l < 5) {
        float4 b0 = *(const float4*)(b2a + 8 * l);
        float4 b1 = *(const float4*)(b2a + 8 * l + 4);
        float4 h0, h1;
        h0.x = fmaxf(acc[0] + b0.x, 0.f); h0.y = fmaxf(acc[1] + b0.y, 0.f);
        h0.z = fmaxf(acc[2] + b0.z, 0.f); h0.w = fmaxf(acc[3] + b0.w, 0.f);
        h1.x = fmaxf(acc[4] + b1.x, 0.f); h1.y = fmaxf(acc[5] + b1.y, 0.f);
        h1.z = fmaxf(acc[6] + b1.z, 0.f); h1.w = fmaxf(acc[7] + b1.w, 0.f);
        *(float4*)&h2s[wid][8 * l] = h0;
        *(float4*)&h2s[wid][8 * l + 4] = h1;
    }
    __threadfence_block();   // same-wave LDS RAW (no cross-wave dependency: each wave owns h2s[wid])

    float logit = -__builtin_inff();
    if (l < NC) {
        float a = b2b[l];
        #pragma unroll 4
        for (int k = 0; k < NC; ++k) a += h2s[wid][k] * W2b[k * NC + l];
        logit = a;
    }
    float m = logit;
    #pragma unroll
    for (int d = 32; d >= 1; d >>= 1) m = fmaxf(m, __shfl_xor(m, d, 64));
    float ev = (l < NC) ? __expf(logit - m) : 0.f;
    float s = ev;
    #pragma unroll
    for (int d = 32; d >= 1; d >>= 1) s += __shfl_xor(s, d, 64);
    if (l < NC) out[(size_t)n * NC + l] = ev / s;
}

extern "C" void kernel_launch(void* const* d_in, const int* in_sizes, int n_in,
                              void* d_out, int out_size, void* d_ws, size_t ws_size,
                              hipStream_t stream) {
    const float* x   = (const float*)d_in[0];
    const int2*  ei  = (const int2*)d_in[1];
    const float* W1a = (const float*)d_in[2];
    const float* b1a = (const float*)d_in[3];
    const float* W1b = (const float*)d_in[4];
    const float* b1b = (const float*)d_in[5];
    const float* W2a = (const float*)d_in[6];
    const float* b2a = (const float*)d_in[7];
    const float* W2b = (const float*)d_in[8];
    const float* b2b = (const float*)d_in[9];
    float* out = (float*)d_out;

    char* w = (char*)d_ws;
    int*    deg    = (int*)(w + 0);           // 100001 ints -> row_ptr after scan
    int*    cursor = (int*)(w + 400128);      // 100000 ints (init to row_ptr by scan2)
    int*    bsums  = (int*)(w + 800128);      // 16 ints
    int*    csr    = (int*)(w + 800192);      // 1.6M ints
    __half* xh     = (__half*)(w + 7200256);  // 100000x128 fp16
    __half* hp     = (__half*)(w + 32800256); // 100000x128 fp16 (agg result)
    __half* y      = (__half*)(w + 58400256); // 100000x40 fp16 (16B-aligned)
    _Float16* Pa   = (_Float16*)(w + 66400256); // 32KB W1a frags
    _Float16* Pb   = (_Float16*)(w + 66433024); // 32KB W1b frags
    _Float16* Pc   = (_Float16*)(w + 66465792); // 12KB W2a frags (padded to 48 cols)
    // total ws needed: 66,478,080 bytes

    hipMemsetAsync(w, 0, 400128, stream);  // zero deg only (cursor/bsums written before read)
    k_hist_cvt<<<N_EDGES / 256, 256, 0, stream>>>(ei, deg, x, xh);
    k_scan1   <<<SCAN_NB, SCAN_T, 0, stream>>>(deg, bsums);
    k_scan2   <<<SCAN_NB, SCAN_T, 0, stream>>>(deg, bsums, cursor);
    k_fill    <<<N_EDGES / 256, 256, 0, stream>>>(ei, cursor, csr);
    k_pack    <<<19, 256, 0, stream>>>(W1a, W1b, W2a, Pa, Pb, Pc);
    k_gather1 <<<N_NODES / 4, 256, 0, stream>>>((const __half2*)xh, deg, csr, (__half2*)hp);
    k_mlp     <<<(N_NODES + 63) / 64, 256, 0, stream>>>(hp, Pa, Pb, Pc, b1a, b1b, y);
    k_gather2 <<<N_NODES / 4, 256, 0, stream>>>(y, deg, csr, b2a, W2b, b2b, out);
}